// Round 11
// baseline (5705.230 us; speedup 1.0000x reference)
//
#include <hip/hip_runtime.h>
#include <stdint.h>
#include <math.h>

// Replicate jax.random threefry2x32 exactly (jax_threefry_partitionable=True).
#define PARTITIONABLE 1

namespace {

constexpr int kB = 4096;
constexpr int kN = 256;
constexpr int kSweeps = 200;
constexpr int kSamp = 16;                // samples per block
constexpr int kBlocks = kB / kSamp;      // 256 blocks of 512 threads -> 1/CU
// block = 8 waves: waves 0-3 consumers (wave cw: samples cw*4..cw*4+3, ALL
// 256 rows, 4 rows/thread), waves 4-7 producers (next sweep threefry).
// Wave w -> SIMD w%4: every SIMD gets exactly 1 consumer + 1 producer.
// (4 rows, 4 samples)/lane halves spin-LDS reads vs r10's (2,8): the spin
// read count = samples/lane * 32 chunks; LDS b128 broadcast ~24cyc is the
// measured wall (r0/r10 calibration).

struct K2 { uint32_t a, b; };

__host__ __device__ constexpr uint32_t crotl(uint32_t x, int d) {
  return (x << d) | (x >> (32 - d));
}

// Threefry-2x32, 20 rounds, exactly as jax/_src/prng.py
__host__ __device__ constexpr K2 ctf(uint32_t k0, uint32_t k1, uint32_t c0, uint32_t c1) {
  uint32_t ks0 = k0, ks1 = k1, ks2 = k0 ^ k1 ^ 0x1BD11BDAu;
  uint32_t x0 = c0 + ks0, x1 = c1 + ks1;
  const int r0[4] = {13, 15, 26, 6};
  const int r1[4] = {17, 29, 16, 24};
  for (int i = 0; i < 4; ++i) { x0 += x1; x1 = crotl(x1, r0[i]); x1 ^= x0; }
  x0 += ks1; x1 += ks2 + 1u;
  for (int i = 0; i < 4; ++i) { x0 += x1; x1 = crotl(x1, r1[i]); x1 ^= x0; }
  x0 += ks2; x1 += ks0 + 2u;
  for (int i = 0; i < 4; ++i) { x0 += x1; x1 = crotl(x1, r0[i]); x1 ^= x0; }
  x0 += ks0; x1 += ks1 + 3u;
  for (int i = 0; i < 4; ++i) { x0 += x1; x1 = crotl(x1, r1[i]); x1 ^= x0; }
  x0 += ks1; x1 += ks2 + 4u;
  for (int i = 0; i < 4; ++i) { x0 += x1; x1 = crotl(x1, r0[i]); x1 ^= x0; }
  x0 += ks2; x1 += ks0 + 5u;
  return K2{x0, x1};
}

struct KeyTable {
  uint32_t s0k[2];               // key for initial spins (k0)
  uint32_t sk[kSweeps][4];       // per sweep: k1a,k1b (accept), k2a,k2b (mask)
};

constexpr KeyTable make_keys() {
  KeyTable t{};
  K2 root{0u, 42u};              // jax.random.key(42) -> (hi=0, lo=42)
#if PARTITIONABLE
  K2 k0 = ctf(root.a, root.b, 0u, 0u);
  K2 kl = ctf(root.a, root.b, 0u, 1u);
#else
  K2 p0 = ctf(root.a, root.b, 0u, 2u);
  K2 p1 = ctf(root.a, root.b, 1u, 3u);
  K2 k0{p0.a, p1.a};
  K2 kl{p0.b, p1.b};
#endif
  t.s0k[0] = k0.a; t.s0k[1] = k0.b;
  K2 k = kl;
  for (int s = 0; s < kSweeps; ++s) {
#if PARTITIONABLE
    K2 kn = ctf(k.a, k.b, 0u, 0u);
    K2 k1 = ctf(k.a, k.b, 0u, 1u);
    K2 k2 = ctf(k.a, k.b, 0u, 2u);
#else
    K2 q0 = ctf(k.a, k.b, 0u, 3u);
    K2 q1 = ctf(k.a, k.b, 1u, 4u);
    K2 q2 = ctf(k.a, k.b, 2u, 5u);
    K2 kn{q0.a, q1.a};
    K2 k1{q2.a, q0.b};
    K2 k2{q1.b, q2.b};
#endif
    t.sk[s][0] = k1.a; t.sk[s][1] = k1.b;
    t.sk[s][2] = k2.a; t.sk[s][3] = k2.b;
    k = kn;
  }
  return t;
}

__constant__ KeyTable g_keys = make_keys();

__device__ __forceinline__ uint32_t rng_bits32(uint32_t ka, uint32_t kb, uint32_t m) {
#if PARTITIONABLE
  K2 r = ctf(ka, kb, 0u, m);
  return r.a ^ r.b;
#else
  constexpr uint32_t H = (uint32_t)(kB * kN / 2);
  uint32_t p = (m < H) ? m : (m - H);
  K2 r = ctf(ka, kb, p, p + H);
  return (m < H) ? r.a : r.b;
#endif
}

__device__ __forceinline__ float bits_to_uniform(uint32_t bits) {
  // jax: bitcast(bits >> 9 | 0x3f800000) - 1.0
  return __uint_as_float((bits >> 9) | 0x3f800000u) - 1.0f;
}

// prep: betas + TWO permuted J layouts.
// jpA (sweep, (4,4) scheme): lane l owns rows 4l..4l+3; per chunk c the
//   lane's 8 float4 are [rp][rr][f8]:
//   jpA[(((c*64+l)*2+rp)*2+rr)*8+f] = Jsym[4l+2rp+rr][8c+f]
// jpB (final pass, r10 layout):
//   jpB[((rh*32+c)*64+l2)*16+r*8+f] = Jsym[rh*128+2*l2+r][8c+f]
__global__ void prep_kernel(const float* __restrict__ gamma,
                            float* __restrict__ jpA,
                            float* __restrict__ jpB,
                            float* __restrict__ betas) {
  int e = blockIdx.x * blockDim.x + threadIdx.x;   // 0..65535
  int i = e / kN, j = e % kN;
  float v = 0.0f;
  if (i < j) v = gamma[i * kN + j];
  else if (i > j) v = gamma[j * kN + i];
  int c = j >> 3, f = j & 7;
  int l = i >> 2, rp = (i >> 1) & 1, rr = i & 1;
  jpA[(((c * 64 + l) * 2 + rp) * 2 + rr) * 8 + f] = v;
  int rh = i >> 7, l2 = (i & 127) >> 1, r = i & 1;
  jpB[((rh * 32 + c) * 64 + l2) * 16 + r * 8 + f] = v;
  if (e < kSweeps) {
    double lo = log(0.1), hi = log(5.0);
    betas[e] = (float)exp(lo + (hi - lo) * (double)e / (double)(kSweeps - 1));
  }
}

// One VALU op per element: f32 fma with the f16 spin operand converted in-op.
// Conversion of +-1.0h to f32 is exact, then fp32 fma -> bit-identical to
// fmaf(+-1.0f, J, acc). op_sel picks lo/hi half of the packed u32.
#define FMIX_LO(a, w, j)                                                      \
  asm("v_fma_mix_f32 %0, %1, %2, %0 op_sel:[0,0,0] op_sel_hi:[1,0,0]"         \
      : "+v"(a) : "v"(w), "v"(j))
#define FMIX_HI(a, w, j)                                                      \
  asm("v_fma_mix_f32 %0, %1, %2, %0 op_sel:[1,0,0] op_sel_hi:[1,0,0]"         \
      : "+v"(a) : "v"(w), "v"(j))

__global__ __launch_bounds__(512) void anneal_kernel(
    const float* __restrict__ thetas, const float* __restrict__ jpA,
    const float* __restrict__ jpB, const float* __restrict__ betas,
    float* __restrict__ out) {
  // fp16 spins (+1.0h=0x3C00, -1.0h=0xBC00), [buf][g][row], dbuf: 16 KiB
  __shared__ __align__(16) unsigned short sh_h[2][kSamp][kN];
  // packed randoms w = ((b1>>9)<<1)|(b2>>31), one u32/site, dbuf: 32 KiB
  __shared__ __align__(16) uint32_t sh_rand[2][kSamp * kN];
  __shared__ float sh_red[kSamp][4];

  const int tid = threadIdx.x;
  const int lane = tid & 63;
  const int wvid = tid >> 6;                     // wave 0..7 -> SIMD wvid%4
  const bool consumer = (wvid < 4);
  const int b0 = blockIdx.x * kSamp;             // first sample of block

  int cur = 0;

  if (consumer) {
    const int cw = wvid;                         // consumer wave 0..3
    const int gbase = cw * 4;                    // this wave's 4 samples
    const int row0 = 4 * lane;                   // rows row0..row0+3

    float4 th4[4];
    uint2 sreg[4];                               // fp16 pairs: rows(0,1),(2,3)
#pragma unroll
    for (int g = 0; g < 4; ++g)
      th4[g] = *(const float4*)&thetas[(b0 + gbase + g) * kN + row0];

    // s0 = where(bernoulli(k0, 0.5), 1, -1) ; bernoulli = uniform < 0.5
#pragma unroll
    for (int g = 0; g < 4; ++g) {
      uint32_t m0 = (uint32_t)((b0 + gbase + g) * kN + row0);
      uint32_t h[4];
#pragma unroll
      for (int r = 0; r < 4; ++r) {
        float u = bits_to_uniform(
            rng_bits32(g_keys.s0k[0], g_keys.s0k[1], m0 + r));
        h[r] = (u < 0.5f) ? 0x3C00u : 0xBC00u;
      }
      sreg[g].x = h[0] | (h[1] << 16);
      sreg[g].y = h[2] | (h[3] << 16);
      *(uint2*)&sh_h[0][gbase + g][row0] = sreg[g];
    }
    __syncthreads();

    // this lane's coalesced jpA slice: chunk c at jpt[c*512 + 0..7]
    const float4* __restrict__ jpt = (const float4*)jpA + (size_t)lane * 8;

#define LDSPIN4(g, c) (*(const uint4*)&sh_h[cur][gbase + (g)][(c) * 8])
    // consume chunk (8 j) for 4 samples x 4 rows: 128 fma_mix, j ascending.
    // q = sample + 4*row-pair: same 8x16 shape as the proven r10 CONSUME2.
#define CONSUME4(W, J)                                                        \
  _Pragma("unroll")                                                           \
  for (int q = 0; q < 8; ++q) {                                               \
    const int g_ = q & 3, rp_ = q >> 2;                                       \
    FMIX_LO(acc[2*q], W[g_].x, J[rp_*4+0].x); FMIX_HI(acc[2*q], W[g_].x, J[rp_*4+0].y); \
    FMIX_LO(acc[2*q], W[g_].y, J[rp_*4+0].z); FMIX_HI(acc[2*q], W[g_].y, J[rp_*4+0].w); \
    FMIX_LO(acc[2*q], W[g_].z, J[rp_*4+1].x); FMIX_HI(acc[2*q], W[g_].z, J[rp_*4+1].y); \
    FMIX_LO(acc[2*q], W[g_].w, J[rp_*4+1].z); FMIX_HI(acc[2*q], W[g_].w, J[rp_*4+1].w); \
    FMIX_LO(acc[2*q+1], W[g_].x, J[rp_*4+2].x); FMIX_HI(acc[2*q+1], W[g_].x, J[rp_*4+2].y); \
    FMIX_LO(acc[2*q+1], W[g_].y, J[rp_*4+2].z); FMIX_HI(acc[2*q+1], W[g_].y, J[rp_*4+2].w); \
    FMIX_LO(acc[2*q+1], W[g_].z, J[rp_*4+3].x); FMIX_HI(acc[2*q+1], W[g_].z, J[rp_*4+3].y); \
    FMIX_LO(acc[2*q+1], W[g_].w, J[rp_*4+3].z); FMIX_HI(acc[2*q+1], W[g_].w, J[rp_*4+3].w); \
  }
    // rolled 15-iter A/B pipeline (r10-proven shape; do not unroll/min-waves)
#define MATVEC4(acc)                                                          \
  {                                                                           \
    uint4 A[4], Bw[4];                                                        \
    float4 JA[8], JB[8];                                                      \
    _Pragma("unroll")                                                         \
    for (int g = 0; g < 4; ++g) A[g] = LDSPIN4(g, 0);                         \
    _Pragma("unroll")                                                         \
    for (int r = 0; r < 8; ++r) JA[r] = jpt[r];                               \
    _Pragma("unroll 1")                                                       \
    for (int k = 0; k < 15; ++k) {                                            \
      const int c = 2 * k;                                                    \
      _Pragma("unroll")                                                       \
      for (int g = 0; g < 4; ++g) Bw[g] = LDSPIN4(g, c + 1);                  \
      _Pragma("unroll")                                                       \
      for (int r = 0; r < 8; ++r) JB[r] = jpt[(c + 1) * 512 + r];             \
      CONSUME4(A, JA)                                                         \
      _Pragma("unroll")                                                       \
      for (int g = 0; g < 4; ++g) A[g] = LDSPIN4(g, c + 2);                   \
      _Pragma("unroll")                                                       \
      for (int r = 0; r < 8; ++r) JA[r] = jpt[(c + 2) * 512 + r];             \
      CONSUME4(Bw, JB)                                                        \
    }                                                                         \
    _Pragma("unroll")                                                         \
    for (int g = 0; g < 4; ++g) Bw[g] = LDSPIN4(g, 31);                       \
    _Pragma("unroll")                                                         \
    for (int r = 0; r < 8; ++r) JB[r] = jpt[31 * 512 + r];                    \
    CONSUME4(A, JA)                                                           \
    CONSUME4(Bw, JB)                                                          \
  }

#pragma unroll 1
    for (int t = 0; t < kSweeps; ++t) {
      const float beta = betas[t];
      // randoms for this sweep: 4 sites per sample (rows 4l..4l+3)
      uint4 wp[4];
      {
        const uint32_t* __restrict__ rb = &sh_rand[t & 1][row0];
#pragma unroll
        for (int g = 0; g < 4; ++g)
          wp[g] = *(const uint4*)&rb[(gbase + g) * kN];
      }

      float acc[16];
#pragma unroll
      for (int x = 0; x < 16; ++x) acc[x] = 0.0f;
      MATVEC4(acc)

#pragma unroll
      for (int g = 0; g < 4; ++g) {
        uint32_t pk0 = sreg[g].x, pk1 = sreg[g].y;
        float s0 = __uint_as_float(0x3F800000u | ((pk0 << 16) & 0x80000000u));
        float s1 = __uint_as_float(0x3F800000u | (pk0 & 0x80000000u));
        float s2 = __uint_as_float(0x3F800000u | ((pk1 << 16) & 0x80000000u));
        float s3 = __uint_as_float(0x3F800000u | (pk1 & 0x80000000u));
        // acc index: row r of sample g -> acc[2*(g + 4*(r>>1)) + (r&1)]
        float l0 = th4[g].x + acc[2 * g + 0];
        float l1 = th4[g].y + acc[2 * g + 1];
        float l2 = th4[g].z + acc[2 * (g + 4) + 0];
        float l3 = th4[g].w + acc[2 * (g + 4) + 1];
        float p0 = expf(-beta * (-2.0f * s0 * l0));  // (-2*s) exact pow2
        float p1 = expf(-beta * (-2.0f * s1 * l1));
        float p2 = expf(-beta * (-2.0f * s2 * l2));
        float p3 = expf(-beta * (-2.0f * s3 * l3));
        float u0 = __uint_as_float((wp[g].x >> 1) | 0x3f800000u) - 1.0f;
        float u1 = __uint_as_float((wp[g].y >> 1) | 0x3f800000u) - 1.0f;
        float u2 = __uint_as_float((wp[g].z >> 1) | 0x3f800000u) - 1.0f;
        float u3 = __uint_as_float((wp[g].w >> 1) | 0x3f800000u) - 1.0f;
        if ((u0 < p0) && ((wp[g].x & 1u) == 0u)) pk0 ^= 0x8000u;
        if ((u1 < p1) && ((wp[g].y & 1u) == 0u)) pk0 ^= 0x80000000u;
        if ((u2 < p2) && ((wp[g].z & 1u) == 0u)) pk1 ^= 0x8000u;
        if ((u3 < p3) && ((wp[g].w & 1u) == 0u)) pk1 ^= 0x80000000u;
        sreg[g].x = pk0; sreg[g].y = pk1;
        *(uint2*)&sh_h[cur ^ 1][gbase + g][row0] = sreg[g];
      }
      __syncthreads();
      cur ^= 1;
    }

    // ---- final energy pass: EXACT r10 structure (bit-identical tree) ----
    {
      const int oct = cw & 1, rh = cw >> 1;
      const int gb8 = oct * 8;
      const int row0f = rh * 128 + 2 * lane;
      const float4* __restrict__ jptf =
          (const float4*)jpB + (size_t)rh * 8192 + (size_t)lane * 4;

      float accf[16];
#pragma unroll
      for (int x = 0; x < 16; ++x) accf[x] = 0.0f;

#define LDSPIN8(g, c) (*(const uint4*)&sh_h[cur][gb8 + (g)][(c) * 8])
#define CONSUME2F(W, Q0, Q1, Q2, Q3)                                          \
  _Pragma("unroll")                                                           \
  for (int g = 0; g < 8; ++g) {                                               \
    FMIX_LO(accf[2*g], W[g].x, Q0.x); FMIX_HI(accf[2*g], W[g].x, Q0.y);       \
    FMIX_LO(accf[2*g], W[g].y, Q0.z); FMIX_HI(accf[2*g], W[g].y, Q0.w);       \
    FMIX_LO(accf[2*g], W[g].z, Q1.x); FMIX_HI(accf[2*g], W[g].z, Q1.y);       \
    FMIX_LO(accf[2*g], W[g].w, Q1.z); FMIX_HI(accf[2*g], W[g].w, Q1.w);       \
    FMIX_LO(accf[2*g+1], W[g].x, Q2.x); FMIX_HI(accf[2*g+1], W[g].x, Q2.y);   \
    FMIX_LO(accf[2*g+1], W[g].y, Q2.z); FMIX_HI(accf[2*g+1], W[g].y, Q2.w);   \
    FMIX_LO(accf[2*g+1], W[g].z, Q3.x); FMIX_HI(accf[2*g+1], W[g].z, Q3.y);   \
    FMIX_LO(accf[2*g+1], W[g].w, Q3.z); FMIX_HI(accf[2*g+1], W[g].w, Q3.w);   \
  }
      {
        uint4 A[8], Bw[8];
        float4 a0, a1, a2, a3, b0_, b1_, b2_, b3_;
#pragma unroll
        for (int g = 0; g < 8; ++g) A[g] = LDSPIN8(g, 0);
        a0 = jptf[0]; a1 = jptf[1]; a2 = jptf[2]; a3 = jptf[3];
#pragma unroll 1
        for (int k = 0; k < 15; ++k) {
          const int c = 2 * k;
#pragma unroll
          for (int g = 0; g < 8; ++g) Bw[g] = LDSPIN8(g, c + 1);
          b0_ = jptf[(c + 1) * 256 + 0]; b1_ = jptf[(c + 1) * 256 + 1];
          b2_ = jptf[(c + 1) * 256 + 2]; b3_ = jptf[(c + 1) * 256 + 3];
          CONSUME2F(A, a0, a1, a2, a3)
#pragma unroll
          for (int g = 0; g < 8; ++g) A[g] = LDSPIN8(g, c + 2);
          a0 = jptf[(c + 2) * 256 + 0]; a1 = jptf[(c + 2) * 256 + 1];
          a2 = jptf[(c + 2) * 256 + 2]; a3 = jptf[(c + 2) * 256 + 3];
          CONSUME2F(Bw, b0_, b1_, b2_, b3_)
        }
#pragma unroll
        for (int g = 0; g < 8; ++g) Bw[g] = LDSPIN8(g, 31);
        b0_ = jptf[31 * 256 + 0]; b1_ = jptf[31 * 256 + 1];
        b2_ = jptf[31 * 256 + 2]; b3_ = jptf[31 * 256 + 3];
        CONSUME2F(A, a0, a1, a2, a3)
        CONSUME2F(Bw, b0_, b1_, b2_, b3_)
      }

#pragma unroll
      for (int g = 0; g < 8; ++g) {
        uint32_t pk = *(const uint32_t*)&sh_h[cur][gb8 + g][row0f];
        float2 t2 = *(const float2*)&thetas[(b0 + gb8 + g) * kN + row0f];
        float s0f = __uint_as_float(0x3F800000u | ((pk << 16) & 0x80000000u));
        float s1f = __uint_as_float(0x3F800000u | (pk & 0x80000000u));
        float x0 = s0f * t2.x + 0.5f * (s0f * accf[2 * g]);
        float x1 = s1f * t2.y + 0.5f * (s1f * accf[2 * g + 1]);
        // slot-split tree == r10 == original 64-lane shfl tree
#pragma unroll
        for (int off = 16; off > 0; off >>= 1) {
          x0 += __shfl_down(x0, off);
          x1 += __shfl_down(x1, off);
        }
        float v = x0 + x1;
        if (lane == 0)  sh_red[gb8 + g][2 * rh + 0] = v;
        if (lane == 32) sh_red[gb8 + g][2 * rh + 1] = v;
      }
    }
  } else {
    // ---------------- producer waves (4..7) ----------------
    const int p = (wvid - 4) * 64 + lane;          // 0..255, 16 sites each
    {
      const uint32_t k1a = g_keys.sk[0][0], k1b = g_keys.sk[0][1];
      const uint32_t k2a = g_keys.sk[0][2], k2b = g_keys.sk[0][3];
      const uint32_t mb = (uint32_t)(b0 * kN + p * 16);
#pragma unroll 4
      for (int q = 0; q < 16; ++q) {
        uint32_t b1 = rng_bits32(k1a, k1b, mb + q);
        uint32_t b2 = rng_bits32(k2a, k2b, mb + q);
        sh_rand[0][p * 16 + q] = ((b1 >> 9) << 1) | (b2 >> 31);
      }
    }
    __syncthreads();

#pragma unroll 1
    for (int t = 0; t < kSweeps; ++t) {
      if (t + 1 < kSweeps) {
        const uint32_t k1a = g_keys.sk[t + 1][0], k1b = g_keys.sk[t + 1][1];
        const uint32_t k2a = g_keys.sk[t + 1][2], k2b = g_keys.sk[t + 1][3];
        const uint32_t mb = (uint32_t)(b0 * kN + p * 16);
        uint32_t wv[16];
#pragma unroll 4
        for (int q = 0; q < 16; ++q) {
          uint32_t b1 = rng_bits32(k1a, k1b, mb + q);
          uint32_t b2 = rng_bits32(k2a, k2b, mb + q);
          wv[q] = ((b1 >> 9) << 1) | (b2 >> 31);
        }
        uint32_t* dst = &sh_rand[(t + 1) & 1][p * 16];
#pragma unroll
        for (int q = 0; q < 4; ++q) {
          uint4 v; v.x = wv[4*q]; v.y = wv[4*q+1]; v.z = wv[4*q+2]; v.w = wv[4*q+3];
          *(uint4*)(dst + 4 * q) = v;
        }
      }
      __syncthreads();
    }
  }

  __syncthreads();
  if (tid < kSamp) {
    out[b0 + tid] =
        sh_red[tid][0] + sh_red[tid][1] + sh_red[tid][2] + sh_red[tid][3];
  }
}

}  // namespace

extern "C" void kernel_launch(void* const* d_in, const int* in_sizes, int n_in,
                              void* d_out, int out_size, void* d_ws, size_t ws_size,
                              hipStream_t stream) {
  const float* thetas = (const float*)d_in[0];   // [4096, 256]
  const float* gamma  = (const float*)d_in[1];   // [256, 256]
  char* ws = (char*)d_ws;
  float* jpA   = (float*)ws;                               // 256 KiB
  float* jpB   = (float*)(ws + (size_t)kN * kN * 4);       // 256 KiB
  float* betas = (float*)(ws + (size_t)kN * kN * 8);       // 800 B

  hipLaunchKernelGGL(prep_kernel, dim3(kN), dim3(kN), 0, stream,
                     gamma, jpA, jpB, betas);
  hipLaunchKernelGGL(anneal_kernel, dim3(kBlocks), dim3(512), 0, stream,
                     thetas, jpA, jpB, betas, (float*)d_out);
}

// Round 12
// 3520.333 us; speedup vs baseline: 1.6207x; 1.6207x over previous
//
#include <hip/hip_runtime.h>
#include <stdint.h>
#include <math.h>

// Replicate jax.random threefry2x32 exactly (jax_threefry_partitionable=True).
#define PARTITIONABLE 1

namespace {

constexpr int kB = 4096;
constexpr int kN = 256;
constexpr int kSweeps = 200;
constexpr int kSamp = 16;                // samples per block (4 per wave)
constexpr int kBlocks = kB / kSamp;      // 256 blocks of 256 threads -> 1/CU
// Wave-private annealer: each wave owns 4 samples completely. Lane holds
// rows 4l..4l+3 of each (spins = 8 VGPR, fp16-packed). Matvec spin broadcast
// via v_readlane -> SGPR -> v_fma_mix scalar operand. No LDS, no role split.
// J is re-laid-out so every load instruction is a contiguous 1KB wave read
// (16 cachelines, not 64 -> fixes the r10/r11 L1 line-service wall).

struct K2 { uint32_t a, b; };

__host__ __device__ constexpr uint32_t crotl(uint32_t x, int d) {
  return (x << d) | (x >> (32 - d));
}

// Threefry-2x32, 20 rounds, exactly as jax/_src/prng.py
__host__ __device__ constexpr K2 ctf(uint32_t k0, uint32_t k1, uint32_t c0, uint32_t c1) {
  uint32_t ks0 = k0, ks1 = k1, ks2 = k0 ^ k1 ^ 0x1BD11BDAu;
  uint32_t x0 = c0 + ks0, x1 = c1 + ks1;
  const int r0[4] = {13, 15, 26, 6};
  const int r1[4] = {17, 29, 16, 24};
  for (int i = 0; i < 4; ++i) { x0 += x1; x1 = crotl(x1, r0[i]); x1 ^= x0; }
  x0 += ks1; x1 += ks2 + 1u;
  for (int i = 0; i < 4; ++i) { x0 += x1; x1 = crotl(x1, r1[i]); x1 ^= x0; }
  x0 += ks2; x1 += ks0 + 2u;
  for (int i = 0; i < 4; ++i) { x0 += x1; x1 = crotl(x1, r0[i]); x1 ^= x0; }
  x0 += ks0; x1 += ks1 + 3u;
  for (int i = 0; i < 4; ++i) { x0 += x1; x1 = crotl(x1, r1[i]); x1 ^= x0; }
  x0 += ks1; x1 += ks2 + 4u;
  for (int i = 0; i < 4; ++i) { x0 += x1; x1 = crotl(x1, r0[i]); x1 ^= x0; }
  x0 += ks2; x1 += ks0 + 5u;
  return K2{x0, x1};
}

struct KeyTable {
  uint32_t s0k[2];               // key for initial spins (k0)
  uint32_t sk[kSweeps][4];       // per sweep: k1a,k1b (accept), k2a,k2b (mask)
};

constexpr KeyTable make_keys() {
  KeyTable t{};
  K2 root{0u, 42u};              // jax.random.key(42) -> (hi=0, lo=42)
#if PARTITIONABLE
  K2 k0 = ctf(root.a, root.b, 0u, 0u);
  K2 kl = ctf(root.a, root.b, 0u, 1u);
#else
  K2 p0 = ctf(root.a, root.b, 0u, 2u);
  K2 p1 = ctf(root.a, root.b, 1u, 3u);
  K2 k0{p0.a, p1.a};
  K2 kl{p0.b, p1.b};
#endif
  t.s0k[0] = k0.a; t.s0k[1] = k0.b;
  K2 k = kl;
  for (int s = 0; s < kSweeps; ++s) {
#if PARTITIONABLE
    K2 kn = ctf(k.a, k.b, 0u, 0u);
    K2 k1 = ctf(k.a, k.b, 0u, 1u);
    K2 k2 = ctf(k.a, k.b, 0u, 2u);
#else
    K2 q0 = ctf(k.a, k.b, 0u, 3u);
    K2 q1 = ctf(k.a, k.b, 1u, 4u);
    K2 q2 = ctf(k.a, k.b, 2u, 5u);
    K2 kn{q0.a, q1.a};
    K2 k1{q2.a, q0.b};
    K2 k2{q1.b, q2.b};
#endif
    t.sk[s][0] = k1.a; t.sk[s][1] = k1.b;
    t.sk[s][2] = k2.a; t.sk[s][3] = k2.b;
    k = kn;
  }
  return t;
}

__constant__ KeyTable g_keys = make_keys();

__device__ __forceinline__ uint32_t rng_bits32(uint32_t ka, uint32_t kb, uint32_t m) {
#if PARTITIONABLE
  K2 r = ctf(ka, kb, 0u, m);
  return r.a ^ r.b;
#else
  constexpr uint32_t H = (uint32_t)(kB * kN / 2);
  uint32_t p = (m < H) ? m : (m - H);
  K2 r = ctf(ka, kb, p, p + H);
  return (m < H) ? r.a : r.b;
#endif
}

__device__ __forceinline__ float bits_to_uniform(uint32_t bits) {
  // jax: bitcast(bits >> 9 | 0x3f800000) - 1.0
  return __uint_as_float((bits >> 9) | 0x3f800000u) - 1.0f;
}

// prep: betas + coalesced-permuted J.
// jpA float4 layout [c][slot][lane]: float4 idx = c*512 + slot*64 + l,
//   slot = (i&3)*2 + (f>>2), comp = f&3, where i = 4l + (i&3), j = 8c + f:
//   holds Jsym[4l + (i&3)][8c + (slot&1)*4 + comp].
// A load of (c, slot) across 64 lanes reads 64 contiguous float4 = 1 KB.
__global__ void prep_kernel(const float* __restrict__ gamma,
                            float* __restrict__ jpA,
                            float* __restrict__ betas) {
  int e = blockIdx.x * blockDim.x + threadIdx.x;   // 0..65535
  int i = e / kN, j = e % kN;
  float v = 0.0f;
  if (i < j) v = gamma[i * kN + j];
  else if (i > j) v = gamma[j * kN + i];
  int c = j >> 3, f = j & 7;
  int l = i >> 2, rl_ = i & 3;
  int slot = rl_ * 2 + (f >> 2);
  jpA[(((size_t)c * 512 + slot * 64 + l) << 2) + (f & 3)] = v;
  if (e < kSweeps) {
    double lo = log(0.1), hi = log(5.0);
    betas[e] = (float)exp(lo + (hi - lo) * (double)e / (double)(kSweeps - 1));
  }
}

// fp32 fma with fp16 spin operand converted in-op; spin word is the one
// scalar (SGPR) operand VOP3P allows. Exact: cvt(+-1.0h)=+-1.0f, then fp32
// fma -> bit-identical to fmaf(+-1.0f, J, acc).
#define FMIX_LO_S(a, w, j)                                                    \
  asm("v_fma_mix_f32 %0, %1, %2, %0 op_sel:[0,0,0] op_sel_hi:[1,0,0]"         \
      : "+v"(a) : "s"(w), "v"(j))
#define FMIX_HI_S(a, w, j)                                                    \
  asm("v_fma_mix_f32 %0, %1, %2, %0 op_sel:[1,0,0] op_sel_hi:[1,0,0]"         \
      : "+v"(a) : "s"(w), "v"(j))

__global__ __launch_bounds__(256, 1) void anneal_kernel(
    const float* __restrict__ thetas, const float* __restrict__ jpA,
    const float* __restrict__ betas, float* __restrict__ out) {
  const int tid = threadIdx.x;
  const int lane = tid & 63;
  const int wvid = tid >> 6;                 // wave 0..3 -> SIMD wvid
  const int b0 = blockIdx.x * kSamp;
  const int gbase = wvid * 4;                // this wave's 4 samples
  const int row0 = 4 * lane;                 // this lane's rows (all samples)

  float4 th4[4];
  uint2 sreg[4];   // fp16 spins: .x = rows 4l,4l+1 (lo,hi); .y = 4l+2,4l+3
#pragma unroll
  for (int g = 0; g < 4; ++g)
    th4[g] = *(const float4*)&thetas[(b0 + gbase + g) * kN + row0];

  // s0 = where(bernoulli(k0, 0.5), 1, -1) ; bernoulli = uniform < 0.5
#pragma unroll
  for (int g = 0; g < 4; ++g) {
    uint32_t m0 = (uint32_t)((b0 + gbase + g) * kN + row0);
    uint32_t h[4];
#pragma unroll
    for (int r = 0; r < 4; ++r) {
      float u = bits_to_uniform(rng_bits32(g_keys.s0k[0], g_keys.s0k[1], m0 + r));
      h[r] = (u < 0.5f) ? 0x3C00u : 0xBC00u;
    }
    sreg[g].x = h[0] | (h[1] << 16);
    sreg[g].y = h[2] | (h[3] << 16);
  }

  // lane's J stream: float4 (c, slot) at jp4[c*512 + slot*64]
  const float4* __restrict__ jp4 = (const float4*)jpA + lane;

  // chunk c covers j = 8c..8c+7; spins for it live in lanes 2c, 2c+1:
  // f=0,1 -> w0=(x of lane 2c); f=2,3 -> w1=(y of 2c); f=4,5 -> w2=(x of
  // 2c+1); f=6,7 -> w3=(y of 2c+1); half = f&1. J: row r, f -> Jw[r*2+(f>>2)]
  // comp f&3. Chain (g,r) consumes f ascending -> exact j order.
#define CONSUME_RL(c, Jw)                                                     \
  _Pragma("unroll")                                                           \
  for (int g = 0; g < 4; ++g) {                                               \
    const uint32_t w0 = (uint32_t)__builtin_amdgcn_readlane((int)sreg[g].x, 2*(c));     \
    const uint32_t w1 = (uint32_t)__builtin_amdgcn_readlane((int)sreg[g].y, 2*(c));     \
    const uint32_t w2 = (uint32_t)__builtin_amdgcn_readlane((int)sreg[g].x, 2*(c)+1);   \
    const uint32_t w3 = (uint32_t)__builtin_amdgcn_readlane((int)sreg[g].y, 2*(c)+1);   \
    _Pragma("unroll")                                                         \
    for (int r = 0; r < 4; ++r) {                                             \
      FMIX_LO_S(acc[4*g+r], w0, Jw[r*2+0].x);                                 \
      FMIX_HI_S(acc[4*g+r], w0, Jw[r*2+0].y);                                 \
      FMIX_LO_S(acc[4*g+r], w1, Jw[r*2+0].z);                                 \
      FMIX_HI_S(acc[4*g+r], w1, Jw[r*2+0].w);                                 \
      FMIX_LO_S(acc[4*g+r], w2, Jw[r*2+1].x);                                 \
      FMIX_HI_S(acc[4*g+r], w2, Jw[r*2+1].y);                                 \
      FMIX_LO_S(acc[4*g+r], w3, Jw[r*2+1].z);                                 \
      FMIX_HI_S(acc[4*g+r], w3, Jw[r*2+1].w);                                 \
    }                                                                         \
  }

  // rolled A/B pipeline over 32 chunks; J window prefetch one chunk ahead
#define MATVEC_RL(acc)                                                        \
  {                                                                           \
    float4 JA[8], JB[8];                                                      \
    _Pragma("unroll")                                                         \
    for (int r = 0; r < 8; ++r) JA[r] = jp4[r * 64];                          \
    _Pragma("unroll 1")                                                       \
    for (int k = 0; k < 16; ++k) {                                            \
      const int cA = 2 * k;                                                   \
      _Pragma("unroll")                                                       \
      for (int r = 0; r < 8; ++r) JB[r] = jp4[(cA + 1) * 512 + r * 64];       \
      CONSUME_RL(cA, JA)                                                      \
      if (k < 15) {                                                           \
        _Pragma("unroll")                                                     \
        for (int r = 0; r < 8; ++r) JA[r] = jp4[(cA + 2) * 512 + r * 64];     \
      }                                                                       \
      CONSUME_RL(cA + 1, JB)                                                  \
    }                                                                         \
  }

#pragma unroll 1
  for (int t = 0; t < kSweeps; ++t) {
    const float beta = betas[t];

    // RNG first (independent of spins): fills J-load latency at sweep start
    const uint32_t k1a = g_keys.sk[t][0], k1b = g_keys.sk[t][1];
    const uint32_t k2a = g_keys.sk[t][2], k2b = g_keys.sk[t][3];
    float u1f[16];
    uint32_t mbits = 0;                      // bit = 1 -> mask fails (no flip)
#pragma unroll
    for (int g = 0; g < 4; ++g) {
#pragma unroll
      for (int r = 0; r < 4; ++r) {
        uint32_t m = (uint32_t)((b0 + gbase + g) * kN + row0 + r);
        uint32_t b1 = rng_bits32(k1a, k1b, m);
        uint32_t b2 = rng_bits32(k2a, k2b, m);
        u1f[4 * g + r] = bits_to_uniform(b1);
        mbits |= (b2 >> 31) << (4 * g + r);  // u2<0.5 <=> bit31==0
      }
    }

    float acc[16];
#pragma unroll
    for (int x = 0; x < 16; ++x) acc[x] = 0.0f;
    MATVEC_RL(acc)

#pragma unroll
    for (int g = 0; g < 4; ++g) {
      uint32_t px = sreg[g].x, py = sreg[g].y;
      float s0 = __uint_as_float(0x3F800000u | ((px << 16) & 0x80000000u));
      float s1 = __uint_as_float(0x3F800000u | (px & 0x80000000u));
      float s2 = __uint_as_float(0x3F800000u | ((py << 16) & 0x80000000u));
      float s3 = __uint_as_float(0x3F800000u | (py & 0x80000000u));
      float l0 = th4[g].x + acc[4 * g + 0];
      float l1 = th4[g].y + acc[4 * g + 1];
      float l2 = th4[g].z + acc[4 * g + 2];
      float l3 = th4[g].w + acc[4 * g + 3];
      float p0 = expf(-beta * (-2.0f * s0 * l0));   // (-2*s) exact pow2
      float p1 = expf(-beta * (-2.0f * s1 * l1));
      float p2 = expf(-beta * (-2.0f * s2 * l2));
      float p3 = expf(-beta * (-2.0f * s3 * l3));
      if ((u1f[4*g+0] < p0) && !((mbits >> (4*g+0)) & 1u)) px ^= 0x8000u;
      if ((u1f[4*g+1] < p1) && !((mbits >> (4*g+1)) & 1u)) px ^= 0x80000000u;
      if ((u1f[4*g+2] < p2) && !((mbits >> (4*g+2)) & 1u)) py ^= 0x8000u;
      if ((u1f[4*g+3] < p3) && !((mbits >> (4*g+3)) & 1u)) py ^= 0x80000000u;
      sreg[g].x = px; sreg[g].y = py;
    }
    // waves are independent; barrier only keeps the 4 waves chunk-aligned
    // so they share each J slice while it is L1-resident
    __syncthreads();
  }

  // E_b = sum_i s_i*theta_i + 0.5 * sum_i s_i * (Jsym s)_i
  {
    float acc[16];
#pragma unroll
    for (int x = 0; x < 16; ++x) acc[x] = 0.0f;
    MATVEC_RL(acc)

#pragma unroll
    for (int g = 0; g < 4; ++g) {
      uint32_t px = sreg[g].x, py = sreg[g].y;
      float s0 = __uint_as_float(0x3F800000u | ((px << 16) & 0x80000000u));
      float s1 = __uint_as_float(0x3F800000u | (px & 0x80000000u));
      float s2 = __uint_as_float(0x3F800000u | ((py << 16) & 0x80000000u));
      float s3 = __uint_as_float(0x3F800000u | (py & 0x80000000u));
      float v0 = s0 * th4[g].x + 0.5f * (s0 * acc[4 * g + 0]);
      float v1 = s1 * th4[g].y + 0.5f * (s1 * acc[4 * g + 1]);
      float v2 = s2 * th4[g].z + 0.5f * (s2 * acc[4 * g + 2]);
      float v3 = s3 * th4[g].w + 0.5f * (s3 * acc[4 * g + 3]);
      float v = ((v0 + v1) + v2) + v3;       // fp32 regroup ok: bf16 compare
#pragma unroll
      for (int off = 32; off > 0; off >>= 1) v += __shfl_down(v, off);
      if (lane == 0) out[b0 + gbase + g] = v;
    }
  }
}

}  // namespace

extern "C" void kernel_launch(void* const* d_in, const int* in_sizes, int n_in,
                              void* d_out, int out_size, void* d_ws, size_t ws_size,
                              hipStream_t stream) {
  const float* thetas = (const float*)d_in[0];   // [4096, 256]
  const float* gamma  = (const float*)d_in[1];   // [256, 256]
  char* ws = (char*)d_ws;
  float* jpA   = (float*)ws;                               // 256 KiB
  float* betas = (float*)(ws + (size_t)kN * kN * 4);       // 800 B

  hipLaunchKernelGGL(prep_kernel, dim3(kN), dim3(kN), 0, stream,
                     gamma, jpA, betas);
  hipLaunchKernelGGL(anneal_kernel, dim3(kBlocks), dim3(256), 0, stream,
                     thetas, jpA, betas, (float*)d_out);
}

// Round 13
// 2211.210 us; speedup vs baseline: 2.5801x; 1.5920x over previous
//
#include <hip/hip_runtime.h>
#include <stdint.h>
#include <math.h>

// Replicate jax.random threefry2x32 exactly (jax_threefry_partitionable=True).
#define PARTITIONABLE 1

namespace {

constexpr int kB = 4096;
constexpr int kN = 256;
constexpr int kSweeps = 200;
constexpr int kSamp = 16;                // samples per block (two octets)
constexpr int kBlocks = kB / kSamp;      // 256 blocks of 512 threads -> 1/CU
// r10 structure (measured best, 12.3 us/sweep) + two deltas:
//  (1) J layout coalesced: each load instruction reads 64 contiguous float4
//      (16 cachelines instead of 64 -> 4x fewer L1 line lookups).
//  (2) producer sh_rand stores lane-contiguous (16B/lane) -> 0 bank conflicts.
// block = 8 waves: waves 0-3 consumers (wave cw: sample-octet cw&1,
// row-half cw>>1, 2 rows/thread), waves 4-7 producers (next sweep threefry).
// Wave w -> SIMD w%4 gives every SIMD exactly 1 consumer + 1 producer.

struct K2 { uint32_t a, b; };

__host__ __device__ constexpr uint32_t crotl(uint32_t x, int d) {
  return (x << d) | (x >> (32 - d));
}

// Threefry-2x32, 20 rounds, exactly as jax/_src/prng.py
__host__ __device__ constexpr K2 ctf(uint32_t k0, uint32_t k1, uint32_t c0, uint32_t c1) {
  uint32_t ks0 = k0, ks1 = k1, ks2 = k0 ^ k1 ^ 0x1BD11BDAu;
  uint32_t x0 = c0 + ks0, x1 = c1 + ks1;
  const int r0[4] = {13, 15, 26, 6};
  const int r1[4] = {17, 29, 16, 24};
  for (int i = 0; i < 4; ++i) { x0 += x1; x1 = crotl(x1, r0[i]); x1 ^= x0; }
  x0 += ks1; x1 += ks2 + 1u;
  for (int i = 0; i < 4; ++i) { x0 += x1; x1 = crotl(x1, r1[i]); x1 ^= x0; }
  x0 += ks2; x1 += ks0 + 2u;
  for (int i = 0; i < 4; ++i) { x0 += x1; x1 = crotl(x1, r0[i]); x1 ^= x0; }
  x0 += ks0; x1 += ks1 + 3u;
  for (int i = 0; i < 4; ++i) { x0 += x1; x1 = crotl(x1, r1[i]); x1 ^= x0; }
  x0 += ks1; x1 += ks2 + 4u;
  for (int i = 0; i < 4; ++i) { x0 += x1; x1 = crotl(x1, r0[i]); x1 ^= x0; }
  x0 += ks2; x1 += ks0 + 5u;
  return K2{x0, x1};
}

struct KeyTable {
  uint32_t s0k[2];               // key for initial spins (k0)
  uint32_t sk[kSweeps][4];       // per sweep: k1a,k1b (accept), k2a,k2b (mask)
};

constexpr KeyTable make_keys() {
  KeyTable t{};
  K2 root{0u, 42u};              // jax.random.key(42) -> (hi=0, lo=42)
#if PARTITIONABLE
  K2 k0 = ctf(root.a, root.b, 0u, 0u);
  K2 kl = ctf(root.a, root.b, 0u, 1u);
#else
  K2 p0 = ctf(root.a, root.b, 0u, 2u);
  K2 p1 = ctf(root.a, root.b, 1u, 3u);
  K2 k0{p0.a, p1.a};
  K2 kl{p0.b, p1.b};
#endif
  t.s0k[0] = k0.a; t.s0k[1] = k0.b;
  K2 k = kl;
  for (int s = 0; s < kSweeps; ++s) {
#if PARTITIONABLE
    K2 kn = ctf(k.a, k.b, 0u, 0u);
    K2 k1 = ctf(k.a, k.b, 0u, 1u);
    K2 k2 = ctf(k.a, k.b, 0u, 2u);
#else
    K2 q0 = ctf(k.a, k.b, 0u, 3u);
    K2 q1 = ctf(k.a, k.b, 1u, 4u);
    K2 q2 = ctf(k.a, k.b, 2u, 5u);
    K2 kn{q0.a, q1.a};
    K2 k1{q2.a, q0.b};
    K2 k2{q1.b, q2.b};
#endif
    t.sk[s][0] = k1.a; t.sk[s][1] = k1.b;
    t.sk[s][2] = k2.a; t.sk[s][3] = k2.b;
    k = kn;
  }
  return t;
}

__constant__ KeyTable g_keys = make_keys();

__device__ __forceinline__ uint32_t rng_bits32(uint32_t ka, uint32_t kb, uint32_t m) {
#if PARTITIONABLE
  K2 r = ctf(ka, kb, 0u, m);
  return r.a ^ r.b;
#else
  constexpr uint32_t H = (uint32_t)(kB * kN / 2);
  uint32_t p = (m < H) ? m : (m - H);
  K2 r = ctf(ka, kb, p, p + H);
  return (m < H) ? r.a : r.b;
#endif
}

__device__ __forceinline__ float bits_to_uniform(uint32_t bits) {
  // jax: bitcast(bits >> 9 | 0x3f800000) - 1.0
  return __uint_as_float((bits >> 9) | 0x3f800000u) - 1.0f;
}

// prep: betas + coalesced-permuted J.
// float4 idx = rh*8192 + c*256 + slot*64 + l2, comp = f&3
//   where rh=i>>7, l2=(i&127)>>1, r=i&1, c=j>>3, f=j&7, slot=r*2+(f>>2);
//   holds Jsym[rh*128 + 2*l2 + r][8c + 4*(slot&1) + comp].
// A load of (rh,c,slot) across 64 lanes (l2=lane) reads 64 contiguous
// float4 = 1 KB = 16 cachelines (was 64 at the r10 64B-stride layout).
__global__ void prep_kernel(const float* __restrict__ gamma,
                            float* __restrict__ jp,
                            float* __restrict__ betas) {
  int e = blockIdx.x * blockDim.x + threadIdx.x;   // 0..65535
  int i = e / kN, j = e % kN;
  float v = 0.0f;
  if (i < j) v = gamma[i * kN + j];
  else if (i > j) v = gamma[j * kN + i];
  int rh = i >> 7, l2 = (i & 127) >> 1, r = i & 1, c = j >> 3, f = j & 7;
  int slot = r * 2 + (f >> 2);
  jp[(((size_t)rh * 8192 + c * 256 + slot * 64 + l2) << 2) + (f & 3)] = v;
  if (e < kSweeps) {
    double lo = log(0.1), hi = log(5.0);
    betas[e] = (float)exp(lo + (hi - lo) * (double)e / (double)(kSweeps - 1));
  }
}

// One VALU op per element: f32 fma with the f16 spin operand converted in-op.
// Conversion of +-1.0h to f32 is exact, then fp32 fma -> bit-identical to
// fmaf(+-1.0f, J, acc). op_sel picks lo/hi half of the packed u32.
#define FMIX_LO(a, w, j)                                                      \
  asm("v_fma_mix_f32 %0, %1, %2, %0 op_sel:[0,0,0] op_sel_hi:[1,0,0]"         \
      : "+v"(a) : "v"(w), "v"(j))
#define FMIX_HI(a, w, j)                                                      \
  asm("v_fma_mix_f32 %0, %1, %2, %0 op_sel:[1,0,0] op_sel_hi:[1,0,0]"         \
      : "+v"(a) : "v"(w), "v"(j))

__global__ __launch_bounds__(512) void anneal_kernel(
    const float* __restrict__ thetas, const float* __restrict__ jp,
    const float* __restrict__ betas, float* __restrict__ out) {
  // fp16 spins (+1.0h=0x3C00, -1.0h=0xBC00), [buf][g][row], dbuf: 16 KiB
  __shared__ __align__(16) unsigned short sh_h[2][kSamp][kN];
  // packed randoms w = ((b1>>9)<<1)|(b2>>31), one u32/site, dbuf: 32 KiB
  __shared__ __align__(16) uint32_t sh_rand[2][kSamp * kN];
  __shared__ float sh_red[kSamp][4];

  const int tid = threadIdx.x;
  const int lane = tid & 63;
  const int wvid = tid >> 6;                     // wave 0..7 -> SIMD wvid%4
  const bool consumer = (wvid < 4);
  const int b0 = blockIdx.x * kSamp;             // first sample of block

  int cur = 0;

  if (consumer) {
    const int cw = wvid;                         // consumer wave 0..3
    const int oct = cw & 1;                      // sample octet 0/1
    const int rh = cw >> 1;                      // row half 0/1
    const int gbase = oct * 8;                   // first sample of octet
    const int row0 = rh * 128 + 2 * lane;        // rows row0, row0+1

    // th_[2g+r] = theta of (sample gbase+g, row r); sreg[g] = fp16 spin pair
    float th_[16];
    uint32_t sreg[8];
#pragma unroll
    for (int g = 0; g < 8; ++g) {
      float2 t2 = *(const float2*)&thetas[(b0 + gbase + g) * kN + row0];
      th_[2 * g] = t2.x; th_[2 * g + 1] = t2.y;
    }
    // s0 = where(bernoulli(k0, 0.5), 1, -1) ; bernoulli = uniform < 0.5
#pragma unroll
    for (int g = 0; g < 8; ++g) {
      uint32_t m0 = (uint32_t)((b0 + gbase + g) * kN + row0);
      float u0 = bits_to_uniform(rng_bits32(g_keys.s0k[0], g_keys.s0k[1], m0));
      float u1 = bits_to_uniform(rng_bits32(g_keys.s0k[0], g_keys.s0k[1], m0 + 1));
      uint32_t pk = ((u0 < 0.5f) ? 0x3C00u : 0xBC00u) |
                    (((u1 < 0.5f) ? 0x3C00u : 0xBC00u) << 16);
      sreg[g] = pk;
      *(uint32_t*)&sh_h[0][gbase + g][row0] = pk;
    }
    __syncthreads();

    // coalesced J slice: slot s of chunk c at jpt[c*256 + s*64] (lane-contig)
    const float4* __restrict__ jpt =
        (const float4*)jp + (size_t)rh * 8192 + (size_t)lane;

#define LDSPIN(g, c) (*(const uint4*)&sh_h[cur][gbase + (g)][(c) * 8])
    // consume chunk (8 j) for 8 samples x 2 rows: 128 fma_mix, j ascending
#define CONSUME2(W, Q0, Q1, Q2, Q3)                                           \
  _Pragma("unroll")                                                           \
  for (int g = 0; g < 8; ++g) {                                               \
    FMIX_LO(acc[2*g], W[g].x, Q0.x); FMIX_HI(acc[2*g], W[g].x, Q0.y);         \
    FMIX_LO(acc[2*g], W[g].y, Q0.z); FMIX_HI(acc[2*g], W[g].y, Q0.w);         \
    FMIX_LO(acc[2*g], W[g].z, Q1.x); FMIX_HI(acc[2*g], W[g].z, Q1.y);         \
    FMIX_LO(acc[2*g], W[g].w, Q1.z); FMIX_HI(acc[2*g], W[g].w, Q1.w);         \
    FMIX_LO(acc[2*g+1], W[g].x, Q2.x); FMIX_HI(acc[2*g+1], W[g].x, Q2.y);     \
    FMIX_LO(acc[2*g+1], W[g].y, Q2.z); FMIX_HI(acc[2*g+1], W[g].y, Q2.w);     \
    FMIX_LO(acc[2*g+1], W[g].z, Q3.x); FMIX_HI(acc[2*g+1], W[g].z, Q3.y);     \
    FMIX_LO(acc[2*g+1], W[g].w, Q3.z); FMIX_HI(acc[2*g+1], W[g].w, Q3.w);     \
  }
    // matvec body as a statement macro so the A/B pipeline shape is fixed
#define MATVEC(acc)                                                           \
  {                                                                           \
    uint4 A[8], Bw[8];                                                        \
    float4 a0, a1, a2, a3, b0_, b1_, b2_, b3_;                                \
    _Pragma("unroll")                                                         \
    for (int g = 0; g < 8; ++g) A[g] = LDSPIN(g, 0);                          \
    a0 = jpt[0]; a1 = jpt[64]; a2 = jpt[128]; a3 = jpt[192];                  \
    _Pragma("unroll 1")                                                       \
    for (int k = 0; k < 15; ++k) {                                            \
      const int c = 2 * k;                                                    \
      _Pragma("unroll")                                                       \
      for (int g = 0; g < 8; ++g) Bw[g] = LDSPIN(g, c + 1);                   \
      b0_ = jpt[(c + 1) * 256 + 0];   b1_ = jpt[(c + 1) * 256 + 64];          \
      b2_ = jpt[(c + 1) * 256 + 128]; b3_ = jpt[(c + 1) * 256 + 192];         \
      CONSUME2(A, a0, a1, a2, a3)                                             \
      _Pragma("unroll")                                                       \
      for (int g = 0; g < 8; ++g) A[g] = LDSPIN(g, c + 2);                    \
      a0 = jpt[(c + 2) * 256 + 0];   a1 = jpt[(c + 2) * 256 + 64];            \
      a2 = jpt[(c + 2) * 256 + 128]; a3 = jpt[(c + 2) * 256 + 192];           \
      CONSUME2(Bw, b0_, b1_, b2_, b3_)                                        \
    }                                                                         \
    _Pragma("unroll")                                                         \
    for (int g = 0; g < 8; ++g) Bw[g] = LDSPIN(g, 31);                        \
    b0_ = jpt[31 * 256 + 0];   b1_ = jpt[31 * 256 + 64];                      \
    b2_ = jpt[31 * 256 + 128]; b3_ = jpt[31 * 256 + 192];                     \
    CONSUME2(A, a0, a1, a2, a3)                                               \
    CONSUME2(Bw, b0_, b1_, b2_, b3_)                                          \
  }

#pragma unroll 1
    for (int t = 0; t < kSweeps; ++t) {
      const float beta = betas[t];
      // randoms for this sweep (produced last sweep / prologue): 2 sites/g
      uint2 wp[8];
      {
        const uint32_t* __restrict__ rb =
            &sh_rand[t & 1][gbase * kN + rh * 128 + 2 * lane];
#pragma unroll
        for (int g = 0; g < 8; ++g)
          wp[g] = *(const uint2*)&rb[g * kN];
      }

      float acc[16];
#pragma unroll
      for (int x = 0; x < 16; ++x) acc[x] = 0.0f;
      MATVEC(acc)

#pragma unroll
      for (int g = 0; g < 8; ++g) {
        uint32_t pk = sreg[g];
        float s0f = __uint_as_float(0x3F800000u | ((pk << 16) & 0x80000000u));
        float s1f = __uint_as_float(0x3F800000u | (pk & 0x80000000u));
        float l0 = th_[2 * g] + acc[2 * g];
        float l1 = th_[2 * g + 1] + acc[2 * g + 1];
        float d0 = -2.0f * s0f * l0;       // exact: (-2*s) power of two
        float d1 = -2.0f * s1f * l1;
        float p0 = expf(-beta * d0);
        float p1 = expf(-beta * d1);
        float u0 = __uint_as_float((wp[g].x >> 1) | 0x3f800000u) - 1.0f;
        float u1 = __uint_as_float((wp[g].y >> 1) | 0x3f800000u) - 1.0f;
        uint32_t msk = 0u;
        if ((u0 < p0) && ((wp[g].x & 1u) == 0u)) msk |= 0x8000u;
        if ((u1 < p1) && ((wp[g].y & 1u) == 0u)) msk |= 0x80000000u;
        pk ^= msk;                          // flip = fp16 sign flip
        sreg[g] = pk;
        *(uint32_t*)&sh_h[cur ^ 1][gbase + g][row0] = pk;
      }
      __syncthreads();
      cur ^= 1;
    }

    // E_b = sum_i s_i*theta_i + 0.5 * sum_i s_i * (Jsym s)_i
    {
      float acc[16];
#pragma unroll
      for (int x = 0; x < 16; ++x) acc[x] = 0.0f;
      MATVEC(acc)

#pragma unroll
      for (int g = 0; g < 8; ++g) {
        uint32_t pk = sreg[g];
        float s0f = __uint_as_float(0x3F800000u | ((pk << 16) & 0x80000000u));
        float s1f = __uint_as_float(0x3F800000u | (pk & 0x80000000u));
        // identical expression to previous rounds: v = s*th + 0.5f*(s*acc)
        float x0 = s0f * th_[2 * g] + 0.5f * (s0f * acc[2 * g]);
        float x1 = s1f * th_[2 * g + 1] + 0.5f * (s1f * acc[2 * g + 1]);
        // slot-split tree == r10 == original 64-lane shfl tree
#pragma unroll
        for (int off = 16; off > 0; off >>= 1) {
          x0 += __shfl_down(x0, off);
          x1 += __shfl_down(x1, off);
        }
        float v = x0 + x1;
        if (lane == 0)  sh_red[gbase + g][2 * rh + 0] = v;  // rows [rh*128,+64)
        if (lane == 32) sh_red[gbase + g][2 * rh + 1] = v;  // rows [rh*128+64,+64)
      }
    }
  } else {
    // ---------------- producer waves (4..7) ----------------
    // store instruction k covers sites pw*1024 + k*256 + lane*4 + 0..3:
    // lane-contiguous 16B -> conflict-free ds_write_b128 (r10 had 19.7M
    // conflicts from 64B-stride stores).
    const int pw = wvid - 4;                       // 0..3
    {
      const uint32_t k1a = g_keys.sk[0][0], k1b = g_keys.sk[0][1];
      const uint32_t k2a = g_keys.sk[0][2], k2b = g_keys.sk[0][3];
#pragma unroll
      for (int k = 0; k < 4; ++k) {
        const uint32_t site = (uint32_t)(pw * 1024 + k * 256 + lane * 4);
        const uint32_t mb = (uint32_t)(b0 * kN) + site;
        uint32_t wv[4];
#pragma unroll
        for (int e = 0; e < 4; ++e) {
          uint32_t b1 = rng_bits32(k1a, k1b, mb + e);
          uint32_t b2 = rng_bits32(k2a, k2b, mb + e);
          wv[e] = ((b1 >> 9) << 1) | (b2 >> 31);
        }
        uint4 v; v.x = wv[0]; v.y = wv[1]; v.z = wv[2]; v.w = wv[3];
        *(uint4*)&sh_rand[0][site] = v;
      }
    }
    __syncthreads();

#pragma unroll 1
    for (int t = 0; t < kSweeps; ++t) {
      if (t + 1 < kSweeps) {
        const uint32_t k1a = g_keys.sk[t + 1][0], k1b = g_keys.sk[t + 1][1];
        const uint32_t k2a = g_keys.sk[t + 1][2], k2b = g_keys.sk[t + 1][3];
#pragma unroll
        for (int k = 0; k < 4; ++k) {
          const uint32_t site = (uint32_t)(pw * 1024 + k * 256 + lane * 4);
          const uint32_t mb = (uint32_t)(b0 * kN) + site;
          uint32_t wv[4];
#pragma unroll
          for (int e = 0; e < 4; ++e) {
            uint32_t b1 = rng_bits32(k1a, k1b, mb + e);
            uint32_t b2 = rng_bits32(k2a, k2b, mb + e);
            wv[e] = ((b1 >> 9) << 1) | (b2 >> 31);
          }
          uint4 v; v.x = wv[0]; v.y = wv[1]; v.z = wv[2]; v.w = wv[3];
          *(uint4*)&sh_rand[(t + 1) & 1][site] = v;
        }
      }
      __syncthreads();
    }
  }

  __syncthreads();
  if (tid < kSamp) {
    out[b0 + tid] =
        sh_red[tid][0] + sh_red[tid][1] + sh_red[tid][2] + sh_red[tid][3];
  }
}

}  // namespace

extern "C" void kernel_launch(void* const* d_in, const int* in_sizes, int n_in,
                              void* d_out, int out_size, void* d_ws, size_t ws_size,
                              hipStream_t stream) {
  const float* thetas = (const float*)d_in[0];   // [4096, 256]
  const float* gamma  = (const float*)d_in[1];   // [256, 256]
  char* ws = (char*)d_ws;
  float* jp    = (float*)ws;                               // 256 KiB
  float* betas = (float*)(ws + (size_t)kN * kN * 4);       // 800 B

  hipLaunchKernelGGL(prep_kernel, dim3(kN), dim3(kN), 0, stream,
                     gamma, jp, betas);
  hipLaunchKernelGGL(anneal_kernel, dim3(kBlocks), dim3(512), 0, stream,
                     thetas, jp, betas, (float*)d_out);
}